// Round 4
// baseline (2128.002 us; speedup 1.0000x reference)
//
#include <hip/hip_runtime.h>
#include <math.h>

#define N_NODES 50000
#define N_EDGES 500000
#define D 128
#define CAT 384

typedef __bf16 v8bf __attribute__((ext_vector_type(8)));
typedef float v4f __attribute__((ext_vector_type(4)));

__device__ __forceinline__ float gelu_exact(float x) {
    return 0.5f * x * (1.0f + erff(x * 0.70710678118654752440f));
}

__device__ __forceinline__ v8bf cvt8(const float* __restrict__ p) {
    float4 f0 = *(const float4*)p;
    float4 f1 = *(const float4*)(p + 4);
    v8bf r;
    r[0] = (__bf16)f0.x; r[1] = (__bf16)f0.y; r[2] = (__bf16)f0.z; r[3] = (__bf16)f0.w;
    r[4] = (__bf16)f1.x; r[5] = (__bf16)f1.y; r[6] = (__bf16)f1.z; r[7] = (__bf16)f1.w;
    return r;
}

// ---------------------------------------------------------------------------
// Convert all GEMM weights to bf16 once per call, with layouts so every
// B-fragment is a direct aligned 16B load.
//   [0,32768)       WP1[256][128]: j<128: msgW[j][k]  else msgW[j-128][128+k]
//   [32768,65536)   WQ1[256][128]: same from W1
//   [65536,81920)   V3 [128][128]: W1[j][256+k]
//   [81920,83968)   W2B[16][128]
//   [83968,133120)  WIH[384][128]
//   [133120,182272) WHH[384][128]
__global__ __launch_bounds__(256) void k_cvtw(const float* __restrict__ msgW,
                                              const float* __restrict__ W1,
                                              const float* __restrict__ W2,
                                              const float* __restrict__ wih,
                                              const float* __restrict__ whh,
                                              __bf16* __restrict__ WB) {
    int i = blockIdx.x * 256 + threadIdx.x;
    float v;
    if (i < 32768) {
        int j = i >> 7, k = i & 127;
        v = (j < 128) ? msgW[j * CAT + k] : msgW[(j - 128) * CAT + 128 + k];
    } else if (i < 65536) {
        int ii = i - 32768; int j = ii >> 7, k = ii & 127;
        v = (j < 128) ? W1[j * CAT + k] : W1[(j - 128) * CAT + 128 + k];
    } else if (i < 81920) {
        int ii = i - 65536; int j = ii >> 7, k = ii & 127;
        v = W1[j * CAT + 256 + k];
    } else if (i < 83968) {
        v = W2[i - 81920];
    } else if (i < 133120) {
        v = wih[i - 83968];
    } else {
        v = whh[i - 133120];
    }
    WB[i] = (__bf16)v;
}

// ---------------------------------------------------------------------------
// RPB[r][j] = bf16( sum_k rel_emb[r][k] * msg_W[j][256+k] + msg_b[j] )
__global__ void k_relpart(const float* __restrict__ rel_emb,
                          const float* __restrict__ msg_W,
                          const float* __restrict__ msg_b,
                          __bf16* __restrict__ RPB) {
    int r = blockIdx.x;
    int j = threadIdx.x;
    const float* er = rel_emb + r * D;
    const float* wr = msg_W + j * CAT + 2 * D;
    float acc = msg_b[j];
    #pragma unroll 8
    for (int k = 0; k < D; ++k) acc += er[k] * wr[k];
    RPB[r * D + j] = (__bf16)acc;
}

// ---------------------------------------------------------------------------
// MFMA node projection, bf16 weights [256][128], bf16 output [N][256].
__global__ __launch_bounds__(256) void k_proj2_mfma(const float* __restrict__ in,
                                                    const __bf16* __restrict__ wb,
                                                    __bf16* __restrict__ out) {
    int t = threadIdx.x;
    int lane = t & 63, wid = t >> 6;
    int g = lane >> 4, c = lane & 15;
    int nbase = blockIdx.x * 64 + wid * 16;

    int nrow = min(nbase + c, N_NODES - 1);
    const float* ir = in + (size_t)nrow * D + g * 8;
    v8bf afrag[4];
    #pragma unroll
    for (int kc = 0; kc < 4; ++kc) afrag[kc] = cvt8(ir + kc * 32);

    #pragma unroll 4
    for (int jt = 0; jt < 16; ++jt) {
        int j = jt * 16 + c;
        const __bf16* wr = wb + (size_t)j * 128 + g * 8;
        v4f acc = (v4f){0.f, 0.f, 0.f, 0.f};
        #pragma unroll
        for (int kc = 0; kc < 4; ++kc)
            acc = __builtin_amdgcn_mfma_f32_16x16x32_bf16(afrag[kc], *(const v8bf*)(wr + kc * 32), acc, 0, 0, 0);
        #pragma unroll
        for (int r = 0; r < 4; ++r) {
            int node = nbase + g * 4 + r;
            if (node < N_NODES) out[(size_t)node * 256 + j] = (__bf16)acc[r];
        }
    }
}

// ---------------------------------------------------------------------------
// 16 edges/block, 16 threads/edge, 8 cols/thread, vectorized bf16 reads.
__global__ __launch_bounds__(256) void k_msg(const __bf16* __restrict__ PSTB,
                                             const __bf16* __restrict__ RPB,
                                             const int* __restrict__ ei,
                                             const int* __restrict__ lab,
                                             float* __restrict__ agg) {
    int t = threadIdx.x;
    int e = blockIdx.x * 16 + (t >> 4);
    int co = (t & 15) * 8;
    int s = ei[e];
    int d = ei[N_EDGES + e];
    int l = lab[e];
    v8bf ps = *(const v8bf*)(PSTB + (size_t)s * 256 + co);
    v8bf pt = *(const v8bf*)(PSTB + (size_t)d * 256 + 128 + co);
    v8bf rp = *(const v8bf*)(RPB + (size_t)l * D + co);
    float* ap = agg + (size_t)d * D + co;
    #pragma unroll
    for (int i = 0; i < 8; ++i) {
        float v = (float)ps[i] + (float)pt[i] + (float)rp[i];
        atomicAdd(ap + i, gelu_exact(v));
    }
}

// ---------------------------------------------------------------------------
// MFMA GRU, bf16 weights (WIH/WHH [384][128]).
__global__ __launch_bounds__(256) void k_gru_mfma(const float* __restrict__ agg,
                                                  const float* __restrict__ nf,
                                                  const __bf16* __restrict__ WIH,
                                                  const __bf16* __restrict__ WHH,
                                                  const float* __restrict__ b_ih,
                                                  const float* __restrict__ b_hh,
                                                  float* __restrict__ nfu) {
    int t = threadIdx.x;
    int lane = t & 63, wid = t >> 6;
    int g = lane >> 4, c = lane & 15;
    int nbase = blockIdx.x * 64 + wid * 16;

    int nrow = min(nbase + c, N_NODES - 1);
    const float* ar = agg + (size_t)nrow * D + g * 8;
    const float* hr = nf + (size_t)nrow * D + g * 8;
    v8bf afrag[4], hfrag[4];
    #pragma unroll
    for (int kc = 0; kc < 4; ++kc) {
        afrag[kc] = cvt8(ar + kc * 32);
        hfrag[kc] = cvt8(hr + kc * 32);
    }

    for (int jt = 0; jt < 8; ++jt) {
        int j = jt * 16 + c;
        const __bf16* wir = WIH + (size_t)j * 128 + g * 8;
        const __bf16* whr = WHH + (size_t)j * 128 + g * 8;
        v4f a_ir = (v4f){0.f,0.f,0.f,0.f}, a_iz = a_ir, a_in = a_ir;
        v4f a_hr = a_ir, a_hz = a_ir, a_hn = a_ir;
        #pragma unroll
        for (int kc = 0; kc < 4; ++kc) {
            a_ir = __builtin_amdgcn_mfma_f32_16x16x32_bf16(afrag[kc], *(const v8bf*)(wir + kc * 32), a_ir, 0, 0, 0);
            a_iz = __builtin_amdgcn_mfma_f32_16x16x32_bf16(afrag[kc], *(const v8bf*)(wir + 128 * 128 + kc * 32), a_iz, 0, 0, 0);
            a_in = __builtin_amdgcn_mfma_f32_16x16x32_bf16(afrag[kc], *(const v8bf*)(wir + 256 * 128 + kc * 32), a_in, 0, 0, 0);
            a_hr = __builtin_amdgcn_mfma_f32_16x16x32_bf16(hfrag[kc], *(const v8bf*)(whr + kc * 32), a_hr, 0, 0, 0);
            a_hz = __builtin_amdgcn_mfma_f32_16x16x32_bf16(hfrag[kc], *(const v8bf*)(whr + 128 * 128 + kc * 32), a_hz, 0, 0, 0);
            a_hn = __builtin_amdgcn_mfma_f32_16x16x32_bf16(hfrag[kc], *(const v8bf*)(whr + 256 * 128 + kc * 32), a_hn, 0, 0, 0);
        }
        float bir = b_ih[j], biz = b_ih[128 + j], bin = b_ih[256 + j];
        float bhr = b_hh[j], bhz = b_hh[128 + j], bhn = b_hh[256 + j];
        #pragma unroll
        for (int r = 0; r < 4; ++r) {
            int node = nbase + g * 4 + r;
            if (node < N_NODES) {
                float irv = a_ir[r] + bir, hrv = a_hr[r] + bhr;
                float izv = a_iz[r] + biz, hzv = a_hz[r] + bhz;
                float inv = a_in[r] + bin, hnv = a_hn[r] + bhn;
                float rg = 1.f / (1.f + expf(-(irv + hrv)));
                float zg = 1.f / (1.f + expf(-(izv + hzv)));
                float ng = tanhf(inv + rg * hnv);
                float h = nf[(size_t)node * D + j];
                nfu[(size_t)node * D + j] = (1.f - zg) * ng + zg * h;
            }
        }
    }
}

// ---------------------------------------------------------------------------
// MFMA classifier: 64 edges/block, 4 waves. QST gathers (bf16) prefetched to
// registers BEFORE GEMM1; bf16 B operands; single barrier.
__global__ __launch_bounds__(256) void k_cls_mfma(const float* __restrict__ ef,
                                                  const __bf16* __restrict__ QSTB,
                                                  const __bf16* __restrict__ V3,
                                                  const float* __restrict__ b1,
                                                  const __bf16* __restrict__ W2B,
                                                  const float* __restrict__ b2,
                                                  const int* __restrict__ ei,
                                                  float* __restrict__ out) {
    __shared__ __align__(16) __bf16 hc_s[64][128];
    __shared__ __align__(16) __bf16 w2_s[16][128];
    int t = threadIdx.x;
    int lane = t & 63, w = t >> 6;
    int g = lane >> 4, c = lane & 15;
    int e0 = blockIdx.x * 64;
    int e_base = e0 + w * 16;

    // stage W2 (bf16) swizzled
    for (int i = t; i < 16 * 128; i += 256) {
        int r = i >> 7, cc = i & 127;
        w2_s[r][cc ^ ((r & 7) << 3)] = W2B[i];
    }

    // prefetch edge indices + QST gathers (issued before GEMM1)
    int sr[4], tr[4];
    #pragma unroll
    for (int r = 0; r < 4; ++r) {
        int e = min(e_base + g * 4 + r, N_EDGES - 1);
        sr[r] = ei[e];
        tr[r] = ei[N_EDGES + e];
    }
    float qsum[4][8];
    #pragma unroll
    for (int r = 0; r < 4; ++r) {
        const __bf16* qs = QSTB + (size_t)sr[r] * 256;
        const __bf16* qt = QSTB + (size_t)tr[r] * 256 + 128;
        #pragma unroll
        for (int jt = 0; jt < 8; ++jt) {
            int j = c + 16 * jt;
            qsum[r][jt] = (float)qs[j] + (float)qt[j];
        }
    }

    // A fragments from ef (fp32 HBM stream)
    int er = min(e_base + c, N_EDGES - 1);
    const float* efr = ef + (size_t)er * D + g * 8;
    v8bf afrag[4];
    #pragma unroll
    for (int kc = 0; kc < 4; ++kc) afrag[kc] = cvt8(efr + kc * 32);

    // GEMM1: B direct bf16 from V3 (L2-hot)
    v4f acc[8];
    #pragma unroll 2
    for (int jt = 0; jt < 8; ++jt) {
        const __bf16* wr = V3 + (size_t)(c + 16 * jt) * 128 + g * 8;
        v4f a4 = (v4f){0.f, 0.f, 0.f, 0.f};
        #pragma unroll
        for (int kc = 0; kc < 4; ++kc)
            a4 = __builtin_amdgcn_mfma_f32_16x16x32_bf16(afrag[kc], *(const v8bf*)(wr + kc * 32), a4, 0, 0, 0);
        acc[jt] = a4;
    }

    // epilogue: add prefetched gathers + bias, gelu -> bf16 hc_s (swizzled)
    #pragma unroll
    for (int r = 0; r < 4; ++r) {
        int el = w * 16 + g * 4 + r;
        int sw = (el & 7) << 3;
        #pragma unroll
        for (int jt = 0; jt < 8; ++jt) {
            int j = c + 16 * jt;
            float v = acc[jt][r] + qsum[r][jt] + b1[j];
            hc_s[el][j ^ sw] = (__bf16)gelu_exact(v);
        }
    }
    __syncthreads();

    // GEMM2
    v4f acc2 = (v4f){0.f, 0.f, 0.f, 0.f};
    int row = w * 16 + c;
    int sw2 = (c & 7) << 3;
    #pragma unroll
    for (int kc = 0; kc < 4; ++kc) {
        v8bf aa = *(const v8bf*)&hc_s[row][(g * 8 + 32 * kc) ^ sw2];
        v8bf bb = *(const v8bf*)&w2_s[c][(g * 8 + 32 * kc) ^ sw2];
        acc2 = __builtin_amdgcn_mfma_f32_16x16x32_bf16(aa, bb, acc2, 0, 0, 0);
    }
    float b2c = b2[c];
    #pragma unroll
    for (int r = 0; r < 4; ++r) {
        int e = e_base + g * 4 + r;
        if (e < N_EDGES) out[(size_t)e * 16 + c] = acc2[r] + b2c;
    }
}

// ---------------------------------------------------------------------------
extern "C" void kernel_launch(void* const* d_in, const int* in_sizes, int n_in,
                              void* d_out, int out_size, void* d_ws, size_t ws_size,
                              hipStream_t stream) {
    const float* nf   = (const float*)d_in[0];
    const float* ef   = (const float*)d_in[1];
    const int*   ei   = (const int*)d_in[2];
    const int*   lab  = (const int*)d_in[3];
    const float* rel  = (const float*)d_in[4];
    const float* msgW = (const float*)d_in[5];
    const float* msgb = (const float*)d_in[6];
    const float* wih  = (const float*)d_in[7];
    const float* whh  = (const float*)d_in[8];
    const float* bih  = (const float*)d_in[9];
    const float* bhh  = (const float*)d_in[10];
    const float* W1   = (const float*)d_in[11];
    const float* b1   = (const float*)d_in[12];
    const float* W2   = (const float*)d_in[13];
    const float* b2   = (const float*)d_in[14];
    float* out = (float*)d_out;

    char* ws = (char*)d_ws;
    __bf16* WB   = (__bf16*)(ws);                       // 364.5 KB weights
    __bf16* RPB  = (__bf16*)(ws + 524288);              // 16 KB
    __bf16* PSTB = (__bf16*)(ws + 1048576);             // 25.6 MB
    float*  AGG  = (float*)(ws + 1048576 + 25600000);   // 25.6 MB
    float*  NFU  = (float*)(ws + 1048576 + 51200000);   // 25.6 MB
    __bf16* QSTB = PSTB;  // PSTB dead after k_msg; reuse

    __bf16* WP1 = WB;
    __bf16* WQ1 = WB + 32768;
    __bf16* V3  = WB + 65536;
    __bf16* W2B = WB + 81920;
    __bf16* WIH = WB + 83968;
    __bf16* WHH = WB + 133120;

    int nblk = (N_NODES + 63) / 64;
    k_cvtw<<<712, 256, 0, stream>>>(msgW, W1, W2, wih, whh, WB);
    k_relpart<<<64, 128, 0, stream>>>(rel, msgW, msgb, RPB);
    k_proj2_mfma<<<nblk, 256, 0, stream>>>(nf, WP1, PSTB);
    hipMemsetAsync(AGG, 0, (size_t)N_NODES * D * sizeof(float), stream);
    k_msg<<<N_EDGES / 16, 256, 0, stream>>>(PSTB, RPB, ei, lab, AGG);
    k_gru_mfma<<<nblk, 256, 0, stream>>>(AGG, nf, WIH, WHH, bih, bhh, NFU);
    k_proj2_mfma<<<nblk, 256, 0, stream>>>(NFU, WQ1, QSTB);
    k_cls_mfma<<<(N_EDGES + 63) / 64, 256, 0, stream>>>(ef, QSTB, V3, b1, W2B, b2, ei, out);
}

// Round 5
// 680.261 us; speedup vs baseline: 3.1282x; 3.1282x over previous
//
#include <hip/hip_runtime.h>
#include <math.h>

#define N_NODES 50000
#define N_EDGES 500000
#define D 128
#define CAT 384

typedef __bf16 v8bf __attribute__((ext_vector_type(8)));
typedef __bf16 v2bf __attribute__((ext_vector_type(2)));
typedef float v4f __attribute__((ext_vector_type(4)));

__device__ __forceinline__ float gelu_exact(float x) {
    return 0.5f * x * (1.0f + erff(x * 0.70710678118654752440f));
}

__device__ __forceinline__ v8bf cvt8(const float* __restrict__ p) {
    float4 f0 = *(const float4*)p;
    float4 f1 = *(const float4*)(p + 4);
    v8bf r;
    r[0] = (__bf16)f0.x; r[1] = (__bf16)f0.y; r[2] = (__bf16)f0.z; r[3] = (__bf16)f0.w;
    r[4] = (__bf16)f1.x; r[5] = (__bf16)f1.y; r[6] = (__bf16)f1.z; r[7] = (__bf16)f1.w;
    return r;
}

// ---------------------------------------------------------------------------
// One-shot bf16 weight conversion (layouts = direct 16B B-fragments).
__global__ __launch_bounds__(256) void k_cvtw(const float* __restrict__ msgW,
                                              const float* __restrict__ W1,
                                              const float* __restrict__ W2,
                                              const float* __restrict__ wih,
                                              const float* __restrict__ whh,
                                              __bf16* __restrict__ WB) {
    int i = blockIdx.x * 256 + threadIdx.x;
    float v;
    if (i < 32768) {
        int j = i >> 7, k = i & 127;
        v = (j < 128) ? msgW[j * CAT + k] : msgW[(j - 128) * CAT + 128 + k];
    } else if (i < 65536) {
        int ii = i - 32768; int j = ii >> 7, k = ii & 127;
        v = (j < 128) ? W1[j * CAT + k] : W1[(j - 128) * CAT + 128 + k];
    } else if (i < 81920) {
        int ii = i - 65536; int j = ii >> 7, k = ii & 127;
        v = W1[j * CAT + 256 + k];
    } else if (i < 83968) {
        v = W2[i - 81920];
    } else if (i < 133120) {
        v = wih[i - 83968];
    } else {
        v = whh[i - 133120];
    }
    WB[i] = (__bf16)v;
}

// ---------------------------------------------------------------------------
__global__ void k_relpart(const float* __restrict__ rel_emb,
                          const float* __restrict__ msg_W,
                          const float* __restrict__ msg_b,
                          __bf16* __restrict__ RPB) {
    int r = blockIdx.x;
    int j = threadIdx.x;
    const float* er = rel_emb + r * D;
    const float* wr = msg_W + j * CAT + 2 * D;
    float acc = msg_b[j];
    #pragma unroll 8
    for (int k = 0; k < D; ++k) acc += er[k] * wr[k];
    RPB[r * D + j] = (__bf16)acc;
}

// ---------------------------------------------------------------------------
// MFMA node projection, bf16 weights [256][128], bf16 output [N][256].
__global__ __launch_bounds__(256) void k_proj2_mfma(const float* __restrict__ in,
                                                    const __bf16* __restrict__ wb,
                                                    __bf16* __restrict__ out) {
    int t = threadIdx.x;
    int lane = t & 63, wid = t >> 6;
    int g = lane >> 4, c = lane & 15;
    int nbase = blockIdx.x * 64 + wid * 16;

    int nrow = min(nbase + c, N_NODES - 1);
    const float* ir = in + (size_t)nrow * D + g * 8;
    v8bf afrag[4];
    #pragma unroll
    for (int kc = 0; kc < 4; ++kc) afrag[kc] = cvt8(ir + kc * 32);

    #pragma unroll 4
    for (int jt = 0; jt < 16; ++jt) {
        int j = jt * 16 + c;
        const __bf16* wr = wb + (size_t)j * 128 + g * 8;
        v4f acc = (v4f){0.f, 0.f, 0.f, 0.f};
        #pragma unroll
        for (int kc = 0; kc < 4; ++kc)
            acc = __builtin_amdgcn_mfma_f32_16x16x32_bf16(afrag[kc], *(const v8bf*)(wr + kc * 32), acc, 0, 0, 0);
        #pragma unroll
        for (int r = 0; r < 4; ++r) {
            int node = nbase + g * 4 + r;
            if (node < N_NODES) out[(size_t)node * 256 + j] = (__bf16)acc[r];
        }
    }
}

// ---------------------------------------------------------------------------
// CSR build: histogram -> scan -> scatter. All int atomics (no write-through
// penalty concern at this volume: 1M int atomics total).
__global__ __launch_bounds__(256) void k_hist(const int* __restrict__ ei,
                                              int* __restrict__ counts) {
    int e = blockIdx.x * 256 + threadIdx.x;
    if (e < N_EDGES) atomicAdd(&counts[ei[N_EDGES + e]], 1);
}

__global__ __launch_bounds__(256) void k_scan(const int* __restrict__ counts,
                                              int* __restrict__ offsets,
                                              int* __restrict__ cursor) {
    __shared__ int part[256];
    int t = threadIdx.x;
    const int CH = 196;                       // 256*196 = 50176 >= 50000
    int lo = t * CH, hi = min(lo + CH, N_NODES);
    int s = 0;
    for (int i = lo; i < hi; ++i) s += counts[i];
    part[t] = s;
    __syncthreads();
    for (int d = 1; d < 256; d <<= 1) {
        int v = (t >= d) ? part[t - d] : 0;
        __syncthreads();
        part[t] += v;
        __syncthreads();
    }
    int run = (t == 0) ? 0 : part[t - 1];
    for (int i = lo; i < hi; ++i) {
        offsets[i] = run;
        cursor[i] = run;
        run += counts[i];
    }
    if (t == 255) offsets[N_NODES] = run;
}

__global__ __launch_bounds__(256) void k_scatter(const int* __restrict__ ei,
                                                 int* __restrict__ cursor,
                                                 int* __restrict__ elist) {
    int e = blockIdx.x * 256 + threadIdx.x;
    if (e < N_EDGES) {
        int slot = atomicAdd(&cursor[ei[N_EDGES + e]], 1);
        elist[slot] = e;
    }
}

// ---------------------------------------------------------------------------
// Aggregation, atomic-free: one wave per target node; lanes cover 2 cols each;
// fp32 register accumulation over the node's edge list.
__global__ __launch_bounds__(256) void k_agg(const __bf16* __restrict__ PSTB,
                                             const __bf16* __restrict__ RPB,
                                             const int* __restrict__ ei,
                                             const int* __restrict__ lab,
                                             const int* __restrict__ offsets,
                                             const int* __restrict__ elist,
                                             float* __restrict__ agg) {
    int t = threadIdx.x;
    int wid = t >> 6, lane = t & 63;
    int n = blockIdx.x * 4 + wid;
    if (n >= N_NODES) return;
    int beg = offsets[n], end = offsets[n + 1];

    v2bf ptv = *(const v2bf*)(PSTB + (size_t)n * 256 + 128 + lane * 2);
    float pt0 = (float)ptv[0], pt1 = (float)ptv[1];

    float a0 = 0.f, a1 = 0.f;
    for (int idx = beg; idx < end; ++idx) {
        int e = elist[idx];
        int s = ei[e];
        int l = lab[e];
        v2bf ps = *(const v2bf*)(PSTB + (size_t)s * 256 + lane * 2);
        v2bf rp = *(const v2bf*)(RPB + (size_t)l * D + lane * 2);
        a0 += gelu_exact((float)ps[0] + pt0 + (float)rp[0]);
        a1 += gelu_exact((float)ps[1] + pt1 + (float)rp[1]);
    }
    *(float2*)(agg + (size_t)n * D + lane * 2) = make_float2(a0, a1);
}

// ---------------------------------------------------------------------------
// MFMA GRU, bf16 weights (WIH/WHH [384][128]).
__global__ __launch_bounds__(256) void k_gru_mfma(const float* __restrict__ agg,
                                                  const float* __restrict__ nf,
                                                  const __bf16* __restrict__ WIH,
                                                  const __bf16* __restrict__ WHH,
                                                  const float* __restrict__ b_ih,
                                                  const float* __restrict__ b_hh,
                                                  float* __restrict__ nfu) {
    int t = threadIdx.x;
    int lane = t & 63, wid = t >> 6;
    int g = lane >> 4, c = lane & 15;
    int nbase = blockIdx.x * 64 + wid * 16;

    int nrow = min(nbase + c, N_NODES - 1);
    const float* ar = agg + (size_t)nrow * D + g * 8;
    const float* hr = nf + (size_t)nrow * D + g * 8;
    v8bf afrag[4], hfrag[4];
    #pragma unroll
    for (int kc = 0; kc < 4; ++kc) {
        afrag[kc] = cvt8(ar + kc * 32);
        hfrag[kc] = cvt8(hr + kc * 32);
    }

    for (int jt = 0; jt < 8; ++jt) {
        int j = jt * 16 + c;
        const __bf16* wir = WIH + (size_t)j * 128 + g * 8;
        const __bf16* whr = WHH + (size_t)j * 128 + g * 8;
        v4f a_ir = (v4f){0.f,0.f,0.f,0.f}, a_iz = a_ir, a_in = a_ir;
        v4f a_hr = a_ir, a_hz = a_ir, a_hn = a_ir;
        #pragma unroll
        for (int kc = 0; kc < 4; ++kc) {
            a_ir = __builtin_amdgcn_mfma_f32_16x16x32_bf16(afrag[kc], *(const v8bf*)(wir + kc * 32), a_ir, 0, 0, 0);
            a_iz = __builtin_amdgcn_mfma_f32_16x16x32_bf16(afrag[kc], *(const v8bf*)(wir + 128 * 128 + kc * 32), a_iz, 0, 0, 0);
            a_in = __builtin_amdgcn_mfma_f32_16x16x32_bf16(afrag[kc], *(const v8bf*)(wir + 256 * 128 + kc * 32), a_in, 0, 0, 0);
            a_hr = __builtin_amdgcn_mfma_f32_16x16x32_bf16(hfrag[kc], *(const v8bf*)(whr + kc * 32), a_hr, 0, 0, 0);
            a_hz = __builtin_amdgcn_mfma_f32_16x16x32_bf16(hfrag[kc], *(const v8bf*)(whr + 128 * 128 + kc * 32), a_hz, 0, 0, 0);
            a_hn = __builtin_amdgcn_mfma_f32_16x16x32_bf16(hfrag[kc], *(const v8bf*)(whr + 256 * 128 + kc * 32), a_hn, 0, 0, 0);
        }
        float bir = b_ih[j], biz = b_ih[128 + j], bin = b_ih[256 + j];
        float bhr = b_hh[j], bhz = b_hh[128 + j], bhn = b_hh[256 + j];
        #pragma unroll
        for (int r = 0; r < 4; ++r) {
            int node = nbase + g * 4 + r;
            if (node < N_NODES) {
                float irv = a_ir[r] + bir, hrv = a_hr[r] + bhr;
                float izv = a_iz[r] + biz, hzv = a_hz[r] + bhz;
                float inv = a_in[r] + bin, hnv = a_hn[r] + bhn;
                float rg = 1.f / (1.f + expf(-(irv + hrv)));
                float zg = 1.f / (1.f + expf(-(izv + hzv)));
                float ng = tanhf(inv + rg * hnv);
                float h = nf[(size_t)node * D + j];
                nfu[(size_t)node * D + j] = (1.f - zg) * ng + zg * h;
            }
        }
    }
}

// ---------------------------------------------------------------------------
// MFMA classifier: 64 edges/block, 4 waves, QST gathers prefetched (r3/r4).
__global__ __launch_bounds__(256) void k_cls_mfma(const float* __restrict__ ef,
                                                  const __bf16* __restrict__ QSTB,
                                                  const __bf16* __restrict__ V3,
                                                  const float* __restrict__ b1,
                                                  const __bf16* __restrict__ W2B,
                                                  const float* __restrict__ b2,
                                                  const int* __restrict__ ei,
                                                  float* __restrict__ out) {
    __shared__ __align__(16) __bf16 hc_s[64][128];
    __shared__ __align__(16) __bf16 w2_s[16][128];
    int t = threadIdx.x;
    int lane = t & 63, w = t >> 6;
    int g = lane >> 4, c = lane & 15;
    int e0 = blockIdx.x * 64;
    int e_base = e0 + w * 16;

    for (int i = t; i < 16 * 128; i += 256) {
        int r = i >> 7, cc = i & 127;
        w2_s[r][cc ^ ((r & 7) << 3)] = W2B[i];
    }

    int sr[4], tr[4];
    #pragma unroll
    for (int r = 0; r < 4; ++r) {
        int e = min(e_base + g * 4 + r, N_EDGES - 1);
        sr[r] = ei[e];
        tr[r] = ei[N_EDGES + e];
    }
    float qsum[4][8];
    #pragma unroll
    for (int r = 0; r < 4; ++r) {
        const __bf16* qs = QSTB + (size_t)sr[r] * 256;
        const __bf16* qt = QSTB + (size_t)tr[r] * 256 + 128;
        #pragma unroll
        for (int jt = 0; jt < 8; ++jt) {
            int j = c + 16 * jt;
            qsum[r][jt] = (float)qs[j] + (float)qt[j];
        }
    }

    int er = min(e_base + c, N_EDGES - 1);
    const float* efr = ef + (size_t)er * D + g * 8;
    v8bf afrag[4];
    #pragma unroll
    for (int kc = 0; kc < 4; ++kc) afrag[kc] = cvt8(efr + kc * 32);

    v4f acc[8];
    #pragma unroll 2
    for (int jt = 0; jt < 8; ++jt) {
        const __bf16* wr = V3 + (size_t)(c + 16 * jt) * 128 + g * 8;
        v4f a4 = (v4f){0.f, 0.f, 0.f, 0.f};
        #pragma unroll
        for (int kc = 0; kc < 4; ++kc)
            a4 = __builtin_amdgcn_mfma_f32_16x16x32_bf16(afrag[kc], *(const v8bf*)(wr + kc * 32), a4, 0, 0, 0);
        acc[jt] = a4;
    }

    #pragma unroll
    for (int r = 0; r < 4; ++r) {
        int el = w * 16 + g * 4 + r;
        int sw = (el & 7) << 3;
        #pragma unroll
        for (int jt = 0; jt < 8; ++jt) {
            int j = c + 16 * jt;
            float v = acc[jt][r] + qsum[r][jt] + b1[j];
            hc_s[el][j ^ sw] = (__bf16)gelu_exact(v);
        }
    }
    __syncthreads();

    v4f acc2 = (v4f){0.f, 0.f, 0.f, 0.f};
    int row = w * 16 + c;
    int sw2 = (c & 7) << 3;
    #pragma unroll
    for (int kc = 0; kc < 4; ++kc) {
        v8bf aa = *(const v8bf*)&hc_s[row][(g * 8 + 32 * kc) ^ sw2];
        v8bf bb = *(const v8bf*)&w2_s[c][(g * 8 + 32 * kc) ^ sw2];
        acc2 = __builtin_amdgcn_mfma_f32_16x16x32_bf16(aa, bb, acc2, 0, 0, 0);
    }
    float b2c = b2[c];
    #pragma unroll
    for (int r = 0; r < 4; ++r) {
        int e = e_base + g * 4 + r;
        if (e < N_EDGES) out[(size_t)e * 16 + c] = acc2[r] + b2c;
    }
}

// ---------------------------------------------------------------------------
extern "C" void kernel_launch(void* const* d_in, const int* in_sizes, int n_in,
                              void* d_out, int out_size, void* d_ws, size_t ws_size,
                              hipStream_t stream) {
    const float* nf   = (const float*)d_in[0];
    const float* ef   = (const float*)d_in[1];
    const int*   ei   = (const int*)d_in[2];
    const int*   lab  = (const int*)d_in[3];
    const float* rel  = (const float*)d_in[4];
    const float* msgW = (const float*)d_in[5];
    const float* msgb = (const float*)d_in[6];
    const float* wih  = (const float*)d_in[7];
    const float* whh  = (const float*)d_in[8];
    const float* bih  = (const float*)d_in[9];
    const float* bhh  = (const float*)d_in[10];
    const float* W1   = (const float*)d_in[11];
    const float* b1   = (const float*)d_in[12];
    const float* W2   = (const float*)d_in[13];
    const float* b2   = (const float*)d_in[14];
    float* out = (float*)d_out;

    char* ws = (char*)d_ws;
    __bf16* WB      = (__bf16*)(ws);                  // 364.5 KB
    __bf16* RPB     = (__bf16*)(ws + 524288);         // 16 KB
    int*    offsets = (int*)(ws + 1048576);           // 200 KB (N+1)
    int*    counts  = (int*)(ws + 1310720);           // 200 KB
    int*    cursor  = (int*)(ws + 1572864);           // 200 KB
    int*    elist   = (int*)(ws + 1835008);           // 2 MB
    __bf16* PSTB    = (__bf16*)(ws + 4194304);        // 25.6 MB
    float*  AGG     = (float*)(ws + 33554432);        // 25.6 MB
    float*  NFU     = (float*)(ws + 62914560);        // 25.6 MB
    __bf16* QSTB    = PSTB;                           // reuse after k_agg

    __bf16* WP1 = WB;
    __bf16* WQ1 = WB + 32768;
    __bf16* V3  = WB + 65536;
    __bf16* W2B = WB + 81920;
    __bf16* WIH = WB + 83968;
    __bf16* WHH = WB + 133120;

    int nblk = (N_NODES + 63) / 64;
    int eblk = (N_EDGES + 255) / 256;

    k_cvtw<<<712, 256, 0, stream>>>(msgW, W1, W2, wih, whh, WB);
    k_relpart<<<64, 128, 0, stream>>>(rel, msgW, msgb, RPB);
    hipMemsetAsync(counts, 0, N_NODES * sizeof(int), stream);
    k_hist<<<eblk, 256, 0, stream>>>(ei, counts);
    k_proj2_mfma<<<nblk, 256, 0, stream>>>(nf, WP1, PSTB);
    k_scan<<<1, 256, 0, stream>>>(counts, offsets, cursor);
    k_scatter<<<eblk, 256, 0, stream>>>(ei, cursor, elist);
    k_agg<<<(N_NODES + 3) / 4, 256, 0, stream>>>(PSTB, RPB, ei, lab, offsets, elist, AGG);
    k_gru_mfma<<<nblk, 256, 0, stream>>>(AGG, nf, WIH, WHH, bih, bhh, NFU);
    k_proj2_mfma<<<nblk, 256, 0, stream>>>(NFU, WQ1, QSTB);
    k_cls_mfma<<<(N_EDGES + 63) / 64, 256, 0, stream>>>(ef, QSTB, V3, b1, W2B, b2, ei, out);
}

// Round 6
// 618.014 us; speedup vs baseline: 3.4433x; 1.1007x over previous
//
#include <hip/hip_runtime.h>
#include <math.h>

#define N_NODES 50000
#define N_EDGES 500000
#define D 128
#define CAT 384

typedef __bf16 v8bf __attribute__((ext_vector_type(8)));
typedef __bf16 v2bf __attribute__((ext_vector_type(2)));
typedef float v4f __attribute__((ext_vector_type(4)));

__device__ __forceinline__ float gelu_exact(float x) {
    return 0.5f * x * (1.0f + erff(x * 0.70710678118654752440f));
}

__device__ __forceinline__ v8bf cvt8(const float* __restrict__ p) {
    float4 f0 = *(const float4*)p;
    float4 f1 = *(const float4*)(p + 4);
    v8bf r;
    r[0] = (__bf16)f0.x; r[1] = (__bf16)f0.y; r[2] = (__bf16)f0.z; r[3] = (__bf16)f0.w;
    r[4] = (__bf16)f1.x; r[5] = (__bf16)f1.y; r[6] = (__bf16)f1.z; r[7] = (__bf16)f1.w;
    return r;
}

// ---------------------------------------------------------------------------
// One-shot bf16 weight conversion (layouts = direct 16B B-fragments).
__global__ __launch_bounds__(256) void k_cvtw(const float* __restrict__ msgW,
                                              const float* __restrict__ W1,
                                              const float* __restrict__ W2,
                                              const float* __restrict__ wih,
                                              const float* __restrict__ whh,
                                              __bf16* __restrict__ WB) {
    int i = blockIdx.x * 256 + threadIdx.x;
    float v;
    if (i < 32768) {
        int j = i >> 7, k = i & 127;
        v = (j < 128) ? msgW[j * CAT + k] : msgW[(j - 128) * CAT + 128 + k];
    } else if (i < 65536) {
        int ii = i - 32768; int j = ii >> 7, k = ii & 127;
        v = (j < 128) ? W1[j * CAT + k] : W1[(j - 128) * CAT + 128 + k];
    } else if (i < 81920) {
        int ii = i - 65536; int j = ii >> 7, k = ii & 127;
        v = W1[j * CAT + 256 + k];
    } else if (i < 83968) {
        v = W2[i - 81920];
    } else if (i < 133120) {
        v = wih[i - 83968];
    } else {
        v = whh[i - 133120];
    }
    WB[i] = (__bf16)v;
}

// ---------------------------------------------------------------------------
__global__ void k_relpart(const float* __restrict__ rel_emb,
                          const float* __restrict__ msg_W,
                          const float* __restrict__ msg_b,
                          __bf16* __restrict__ RPB) {
    int r = blockIdx.x;
    int j = threadIdx.x;
    const float* er = rel_emb + r * D;
    const float* wr = msg_W + j * CAT + 2 * D;
    float acc = msg_b[j];
    #pragma unroll 8
    for (int k = 0; k < D; ++k) acc += er[k] * wr[k];
    RPB[r * D + j] = (__bf16)acc;
}

// ---------------------------------------------------------------------------
// MFMA node projection (fp32 input). Output-col remap: tile col c -> j =
// half*128 + 8c + jt, so each thread's 8 output elems are contiguous (v8bf store).
__global__ __launch_bounds__(256) void k_proj2_f32(const float* __restrict__ in,
                                                   const __bf16* __restrict__ wb,
                                                   __bf16* __restrict__ out) {
    int t = threadIdx.x;
    int lane = t & 63, wid = t >> 6;
    int g = lane >> 4, c = lane & 15;
    int nbase = blockIdx.x * 64 + wid * 16;

    int nrow = min(nbase + c, N_NODES - 1);
    const float* ir = in + (size_t)nrow * D + g * 8;
    v8bf afrag[4];
    #pragma unroll
    for (int kc = 0; kc < 4; ++kc) afrag[kc] = cvt8(ir + kc * 32);

    #pragma unroll
    for (int half = 0; half < 2; ++half) {
        v4f acc[8];
        #pragma unroll 2
        for (int jt = 0; jt < 8; ++jt) {
            const __bf16* wr = wb + (size_t)(half * 128 + 8 * c + jt) * 128 + g * 8;
            v4f a4 = (v4f){0.f, 0.f, 0.f, 0.f};
            #pragma unroll
            for (int kc = 0; kc < 4; ++kc)
                a4 = __builtin_amdgcn_mfma_f32_16x16x32_bf16(afrag[kc], *(const v8bf*)(wr + kc * 32), a4, 0, 0, 0);
            acc[jt] = a4;
        }
        #pragma unroll
        for (int r = 0; r < 4; ++r) {
            int node = nbase + g * 4 + r;
            v8bf o;
            #pragma unroll
            for (int jt = 0; jt < 8; ++jt) o[jt] = (__bf16)acc[jt][r];
            if (node < N_NODES)
                *(v8bf*)(out + (size_t)node * 256 + half * 128 + 8 * c) = o;
        }
    }
}

// bf16-input variant (for NFUB -> QSTB).
__global__ __launch_bounds__(256) void k_proj2_b16(const __bf16* __restrict__ in,
                                                   const __bf16* __restrict__ wb,
                                                   __bf16* __restrict__ out) {
    int t = threadIdx.x;
    int lane = t & 63, wid = t >> 6;
    int g = lane >> 4, c = lane & 15;
    int nbase = blockIdx.x * 64 + wid * 16;

    int nrow = min(nbase + c, N_NODES - 1);
    const __bf16* ir = in + (size_t)nrow * D + g * 8;
    v8bf afrag[4];
    #pragma unroll
    for (int kc = 0; kc < 4; ++kc) afrag[kc] = *(const v8bf*)(ir + kc * 32);

    #pragma unroll
    for (int half = 0; half < 2; ++half) {
        v4f acc[8];
        #pragma unroll 2
        for (int jt = 0; jt < 8; ++jt) {
            const __bf16* wr = wb + (size_t)(half * 128 + 8 * c + jt) * 128 + g * 8;
            v4f a4 = (v4f){0.f, 0.f, 0.f, 0.f};
            #pragma unroll
            for (int kc = 0; kc < 4; ++kc)
                a4 = __builtin_amdgcn_mfma_f32_16x16x32_bf16(afrag[kc], *(const v8bf*)(wr + kc * 32), a4, 0, 0, 0);
            acc[jt] = a4;
        }
        #pragma unroll
        for (int r = 0; r < 4; ++r) {
            int node = nbase + g * 4 + r;
            v8bf o;
            #pragma unroll
            for (int jt = 0; jt < 8; ++jt) o[jt] = (__bf16)acc[jt][r];
            if (node < N_NODES)
                *(v8bf*)(out + (size_t)node * 256 + half * 128 + 8 * c) = o;
        }
    }
}

// ---------------------------------------------------------------------------
// CSR build: histogram -> scan -> scatter.
__global__ __launch_bounds__(256) void k_hist(const int* __restrict__ ei,
                                              int* __restrict__ counts) {
    int e = blockIdx.x * 256 + threadIdx.x;
    if (e < N_EDGES) atomicAdd(&counts[ei[N_EDGES + e]], 1);
}

__global__ __launch_bounds__(256) void k_scan(const int* __restrict__ counts,
                                              int* __restrict__ offsets,
                                              int* __restrict__ cursor) {
    __shared__ int part[256];
    int t = threadIdx.x;
    const int CH = 196;
    int lo = t * CH, hi = min(lo + CH, N_NODES);
    int s = 0;
    for (int i = lo; i < hi; ++i) s += counts[i];
    part[t] = s;
    __syncthreads();
    for (int d = 1; d < 256; d <<= 1) {
        int v = (t >= d) ? part[t - d] : 0;
        __syncthreads();
        part[t] += v;
        __syncthreads();
    }
    int run = (t == 0) ? 0 : part[t - 1];
    for (int i = lo; i < hi; ++i) {
        offsets[i] = run;
        cursor[i] = run;
        run += counts[i];
    }
    if (t == 255) offsets[N_NODES] = run;
}

__global__ __launch_bounds__(256) void k_scatter(const int* __restrict__ ei,
                                                 int* __restrict__ cursor,
                                                 int* __restrict__ elist) {
    int e = blockIdx.x * 256 + threadIdx.x;
    if (e < N_EDGES) {
        int slot = atomicAdd(&cursor[ei[N_EDGES + e]], 1);
        elist[slot] = e;
    }
}

// ---------------------------------------------------------------------------
// Aggregation, atomic-free; one wave per node; index-prefetch pipeline;
// bf16 output (only consumer converts to bf16 anyway).
__global__ __launch_bounds__(256) void k_agg(const __bf16* __restrict__ PSTB,
                                             const __bf16* __restrict__ RPB,
                                             const int* __restrict__ ei,
                                             const int* __restrict__ lab,
                                             const int* __restrict__ offsets,
                                             const int* __restrict__ elist,
                                             __bf16* __restrict__ agg) {
    int t = threadIdx.x;
    int wid = t >> 6, lane = t & 63;
    int n = blockIdx.x * 4 + wid;
    if (n >= N_NODES) return;
    int beg = offsets[n], end = offsets[n + 1];

    v2bf ptv = *(const v2bf*)(PSTB + (size_t)n * 256 + 128 + lane * 2);
    float pt0 = (float)ptv[0], pt1 = (float)ptv[1];

    float a0 = 0.f, a1 = 0.f;
    int idx = beg;
    int s_nx = 0, l_nx = 0;
    if (idx < end) { int e = elist[idx]; s_nx = ei[e]; l_nx = lab[e]; }
    while (idx < end) {
        int s = s_nx, l = l_nx;
        v2bf ps = *(const v2bf*)(PSTB + (size_t)s * 256 + lane * 2);
        v2bf rp = *(const v2bf*)(RPB + (size_t)l * D + lane * 2);
        ++idx;
        if (idx < end) { int e = elist[idx]; s_nx = ei[e]; l_nx = lab[e]; }
        a0 += gelu_exact((float)ps[0] + pt0 + (float)rp[0]);
        a1 += gelu_exact((float)ps[1] + pt1 + (float)rp[1]);
    }
    v2bf o; o[0] = (__bf16)a0; o[1] = (__bf16)a1;
    *(v2bf*)(agg + (size_t)n * D + lane * 2) = o;
}

// ---------------------------------------------------------------------------
// MFMA GRU, output-col remap j = 8c + jt; bf16 agg input, bf16 nfu output.
__global__ __launch_bounds__(256) void k_gru_mfma(const __bf16* __restrict__ agg,
                                                  const float* __restrict__ nf,
                                                  const __bf16* __restrict__ WIH,
                                                  const __bf16* __restrict__ WHH,
                                                  const float* __restrict__ b_ih,
                                                  const float* __restrict__ b_hh,
                                                  __bf16* __restrict__ nfu) {
    int t = threadIdx.x;
    int lane = t & 63, wid = t >> 6;
    int g = lane >> 4, c = lane & 15;
    int nbase = blockIdx.x * 64 + wid * 16;

    int nrow = min(nbase + c, N_NODES - 1);
    const __bf16* ar = agg + (size_t)nrow * D + g * 8;
    const float* hr = nf + (size_t)nrow * D + g * 8;
    v8bf afrag[4], hfrag[4];
    #pragma unroll
    for (int kc = 0; kc < 4; ++kc) {
        afrag[kc] = *(const v8bf*)(ar + kc * 32);
        hfrag[kc] = cvt8(hr + kc * 32);
    }

    // preload h rows (cols 8c..8c+8) for the epilogue
    float h8[4][8];
    #pragma unroll
    for (int r = 0; r < 4; ++r) {
        int node = min(nbase + g * 4 + r, N_NODES - 1);
        float4 f0 = *(const float4*)(nf + (size_t)node * D + 8 * c);
        float4 f1 = *(const float4*)(nf + (size_t)node * D + 8 * c + 4);
        h8[r][0]=f0.x; h8[r][1]=f0.y; h8[r][2]=f0.z; h8[r][3]=f0.w;
        h8[r][4]=f1.x; h8[r][5]=f1.y; h8[r][6]=f1.z; h8[r][7]=f1.w;
    }

    v8bf o[4];
    for (int jt = 0; jt < 8; ++jt) {
        int j = 8 * c + jt;
        const __bf16* wir = WIH + (size_t)j * 128 + g * 8;
        const __bf16* whr = WHH + (size_t)j * 128 + g * 8;
        v4f a_ir = (v4f){0.f,0.f,0.f,0.f}, a_iz = a_ir, a_in = a_ir;
        v4f a_hr = a_ir, a_hz = a_ir, a_hn = a_ir;
        #pragma unroll
        for (int kc = 0; kc < 4; ++kc) {
            a_ir = __builtin_amdgcn_mfma_f32_16x16x32_bf16(afrag[kc], *(const v8bf*)(wir + kc * 32), a_ir, 0, 0, 0);
            a_iz = __builtin_amdgcn_mfma_f32_16x16x32_bf16(afrag[kc], *(const v8bf*)(wir + 128 * 128 + kc * 32), a_iz, 0, 0, 0);
            a_in = __builtin_amdgcn_mfma_f32_16x16x32_bf16(afrag[kc], *(const v8bf*)(wir + 256 * 128 + kc * 32), a_in, 0, 0, 0);
            a_hr = __builtin_amdgcn_mfma_f32_16x16x32_bf16(hfrag[kc], *(const v8bf*)(whr + kc * 32), a_hr, 0, 0, 0);
            a_hz = __builtin_amdgcn_mfma_f32_16x16x32_bf16(hfrag[kc], *(const v8bf*)(whr + 128 * 128 + kc * 32), a_hz, 0, 0, 0);
            a_hn = __builtin_amdgcn_mfma_f32_16x16x32_bf16(hfrag[kc], *(const v8bf*)(whr + 256 * 128 + kc * 32), a_hn, 0, 0, 0);
        }
        float bir = b_ih[j], biz = b_ih[128 + j], bin = b_ih[256 + j];
        float bhr = b_hh[j], bhz = b_hh[128 + j], bhn = b_hh[256 + j];
        #pragma unroll
        for (int r = 0; r < 4; ++r) {
            float irv = a_ir[r] + bir, hrv = a_hr[r] + bhr;
            float izv = a_iz[r] + biz, hzv = a_hz[r] + bhz;
            float inv = a_in[r] + bin, hnv = a_hn[r] + bhn;
            float rg = 1.f / (1.f + expf(-(irv + hrv)));
            float zg = 1.f / (1.f + expf(-(izv + hzv)));
            float ng = tanhf(inv + rg * hnv);
            o[r][jt] = (__bf16)((1.f - zg) * ng + zg * h8[r][jt]);
        }
    }
    #pragma unroll
    for (int r = 0; r < 4; ++r) {
        int node = nbase + g * 4 + r;
        if (node < N_NODES) *(v8bf*)(nfu + (size_t)node * D + 8 * c) = o[r];
    }
}

// ---------------------------------------------------------------------------
// MFMA classifier, output-col remap j = 8c + jt:
//  - QST gathers become 8x coalesced v8bf loads per thread (were 64 scalar)
//  - hc epilogue: one ds_write_b128 per row (chunk-XOR swizzled)
//  - GEMM2 reads conflict-free via the same chunk swizzle
__global__ __launch_bounds__(256) void k_cls_mfma(const float* __restrict__ ef,
                                                  const __bf16* __restrict__ QSTB,
                                                  const __bf16* __restrict__ V3,
                                                  const float* __restrict__ b1,
                                                  const __bf16* __restrict__ W2B,
                                                  const float* __restrict__ b2,
                                                  const int* __restrict__ ei,
                                                  float* __restrict__ out) {
    __shared__ __align__(16) __bf16 hc_s[64][128];
    __shared__ __align__(16) __bf16 w2_s[16][128];
    int t = threadIdx.x;
    int lane = t & 63, w = t >> 6;
    int g = lane >> 4, c = lane & 15;
    int e0 = blockIdx.x * 64;
    int e_base = e0 + w * 16;

    // stage W2 chunk-swizzled: 256 threads x one 16B chunk
    {
        int r = t >> 4, ch = t & 15;
        v8bf v = *(const v8bf*)(W2B + r * 128 + ch * 8);
        *(v8bf*)&w2_s[r][8 * (ch ^ (r & 7))] = v;
    }

    // edge indices (uniform within 16-lane group)
    int sr[4], tr[4];
    #pragma unroll
    for (int r = 0; r < 4; ++r) {
        int e = min(e_base + g * 4 + r, N_EDGES - 1);
        sr[r] = ei[e];
        tr[r] = ei[N_EDGES + e];
    }
    // vector QST gathers: cols [8c,8c+8) of src half / tgt half
    v8bf qsv[4], qtv[4];
    #pragma unroll
    for (int r = 0; r < 4; ++r) {
        qsv[r] = *(const v8bf*)(QSTB + (size_t)sr[r] * 256 + 8 * c);
        qtv[r] = *(const v8bf*)(QSTB + (size_t)tr[r] * 256 + 128 + 8 * c);
    }
    float4 b1a = *(const float4*)(b1 + 8 * c);
    float4 b1b = *(const float4*)(b1 + 8 * c + 4);
    float b1r[8] = {b1a.x, b1a.y, b1a.z, b1a.w, b1b.x, b1b.y, b1b.z, b1b.w};

    // A fragments from ef
    int er = min(e_base + c, N_EDGES - 1);
    const float* efr = ef + (size_t)er * D + g * 8;
    v8bf afrag[4];
    #pragma unroll
    for (int kc = 0; kc < 4; ++kc) afrag[kc] = cvt8(efr + kc * 32);

    // GEMM1: B row = 8c + jt
    v4f acc[8];
    #pragma unroll 2
    for (int jt = 0; jt < 8; ++jt) {
        const __bf16* wr = V3 + (size_t)(8 * c + jt) * 128 + g * 8;
        v4f a4 = (v4f){0.f, 0.f, 0.f, 0.f};
        #pragma unroll
        for (int kc = 0; kc < 4; ++kc)
            a4 = __builtin_amdgcn_mfma_f32_16x16x32_bf16(afrag[kc], *(const v8bf*)(wr + kc * 32), a4, 0, 0, 0);
        acc[jt] = a4;
    }

    // epilogue: fused gather-add + gelu -> one v8bf LDS store per row
    #pragma unroll
    for (int r = 0; r < 4; ++r) {
        int el = w * 16 + g * 4 + r;
        v8bf o;
        #pragma unroll
        for (int jt = 0; jt < 8; ++jt) {
            float v = acc[jt][r] + (float)qsv[r][jt] + (float)qtv[r][jt] + b1r[jt];
            o[jt] = (__bf16)gelu_exact(v);
        }
        *(v8bf*)&hc_s[el][8 * (c ^ (el & 7))] = o;
    }
    __syncthreads();

    // GEMM2: A = hc rows, B = W2 (both chunk-swizzled)
    v4f acc2 = (v4f){0.f, 0.f, 0.f, 0.f};
    int arow = w * 16 + c;
    #pragma unroll
    for (int kc = 0; kc < 4; ++kc) {
        int ch = g + 4 * kc;
        v8bf aa = *(const v8bf*)&hc_s[arow][8 * (ch ^ (c & 7))];
        v8bf bb = *(const v8bf*)&w2_s[c][8 * (ch ^ (c & 7))];
        acc2 = __builtin_amdgcn_mfma_f32_16x16x32_bf16(aa, bb, acc2, 0, 0, 0);
    }
    float b2c = b2[c];
    #pragma unroll
    for (int r = 0; r < 4; ++r) {
        int e = e_base + g * 4 + r;
        if (e < N_EDGES) out[(size_t)e * 16 + c] = acc2[r] + b2c;
    }
}

// ---------------------------------------------------------------------------
extern "C" void kernel_launch(void* const* d_in, const int* in_sizes, int n_in,
                              void* d_out, int out_size, void* d_ws, size_t ws_size,
                              hipStream_t stream) {
    const float* nf   = (const float*)d_in[0];
    const float* ef   = (const float*)d_in[1];
    const int*   ei   = (const int*)d_in[2];
    const int*   lab  = (const int*)d_in[3];
    const float* rel  = (const float*)d_in[4];
    const float* msgW = (const float*)d_in[5];
    const float* msgb = (const float*)d_in[6];
    const float* wih  = (const float*)d_in[7];
    const float* whh  = (const float*)d_in[8];
    const float* bih  = (const float*)d_in[9];
    const float* bhh  = (const float*)d_in[10];
    const float* W1   = (const float*)d_in[11];
    const float* b1   = (const float*)d_in[12];
    const float* W2   = (const float*)d_in[13];
    const float* b2   = (const float*)d_in[14];
    float* out = (float*)d_out;

    char* ws = (char*)d_ws;
    __bf16* WB      = (__bf16*)(ws);                  // 364.5 KB
    __bf16* RPB     = (__bf16*)(ws + 524288);         // 16 KB
    int*    offsets = (int*)(ws + 1048576);           // 200 KB (N+1)
    int*    counts  = (int*)(ws + 1310720);           // 200 KB
    int*    cursor  = (int*)(ws + 1572864);           // 200 KB
    int*    elist   = (int*)(ws + 1835008);           // 2 MB
    __bf16* PSTB    = (__bf16*)(ws + 4194304);        // 25.6 MB
    __bf16* AGG     = (__bf16*)(ws + 33554432);       // 12.8 MB
    __bf16* NFUB    = (__bf16*)(ws + 50331648);       // 12.8 MB
    __bf16* QSTB    = PSTB;                           // reuse after k_agg

    __bf16* WP1 = WB;
    __bf16* WQ1 = WB + 32768;
    __bf16* V3  = WB + 65536;
    __bf16* W2B = WB + 81920;
    __bf16* WIH = WB + 83968;
    __bf16* WHH = WB + 133120;

    int nblk = (N_NODES + 63) / 64;
    int eblk = (N_EDGES + 255) / 256;

    k_cvtw<<<712, 256, 0, stream>>>(msgW, W1, W2, wih, whh, WB);
    k_relpart<<<64, 128, 0, stream>>>(rel, msgW, msgb, RPB);
    hipMemsetAsync(counts, 0, N_NODES * sizeof(int), stream);
    k_hist<<<eblk, 256, 0, stream>>>(ei, counts);
    k_proj2_f32<<<nblk, 256, 0, stream>>>(nf, WP1, PSTB);
    k_scan<<<1, 256, 0, stream>>>(counts, offsets, cursor);
    k_scatter<<<eblk, 256, 0, stream>>>(ei, cursor, elist);
    k_agg<<<(N_NODES + 3) / 4, 256, 0, stream>>>(PSTB, RPB, ei, lab, offsets, elist, AGG);
    k_gru_mfma<<<nblk, 256, 0, stream>>>(AGG, nf, WIH, WHH, bih, bhh, NFUB);
    k_proj2_b16<<<nblk, 256, 0, stream>>>(NFUB, WQ1, QSTB);
    k_cls_mfma<<<(N_EDGES + 63) / 64, 256, 0, stream>>>(ef, QSTB, V3, b1, W2B, b2, ei, out);
}